// Round 4
// baseline (3630.803 us; speedup 1.0000x reference)
//
#include <hip/hip_runtime.h>

// ContinuousLSTMLayer B=256,S=512,F=64,H=128; 8192 sequential RK4 stages.
// v8 = v7 + sched_group_barrier MFMA<->VALU interleave (T19).
// v7 PMC: stage 1090cy, MFMA-busy 610cy (=620 model), 480cy pipe-idle.
// Residual diagnosis: in-order issue clusters [16 MFMA][S1 ~45 VALU][tail];
// pipes alternate. Fix: one scheduling region per stage + SGB pattern
//   DS_READ(4) ; MFMA(6) warm-up ; 10 x { MFMA(1) ; VALU|TRANS(4) }
// so each wave issues S1/tail VALU in the ~39cy gaps between its MFMA
// accepts. Warm-up of 6 gives ci2/ci3 (S1's first operands) ~120cy before
// the first dependent VALU group. Divergent quad==0 ds_write replaced by
// predicated pointer-select (dump buffer) to keep the region a single BB.
// Everything else identical to v7 (ifg-at-top via ap, lgkm-only barrier,
// 1-stage-deferred c-path, o split 4x1, amortized x-projection).

#define B_N 256
#define S_N 512
#define F_N 64
#define H_N 128

typedef _Float16 v8h __attribute__((ext_vector_type(8)));
typedef float v4f __attribute__((ext_vector_type(4)));

#define PIN_V(x) asm("" : "+v"(x))
#define MFMA16(a, b, c) __builtin_amdgcn_mfma_f32_16x16x32_f16((a), (b), (c), 0, 0, 0)
#define SB0() __builtin_amdgcn_sched_barrier(0)
#define SGB(m, n) __builtin_amdgcn_sched_group_barrier((m), (n), 0)
// LLVM SchedGroupMask bits: VALU=0x2, MFMA=0x8, DS_READ=0x100, TRANS=0x400
#define M_MFMA 0x8
#define M_VALU 0x402   // VALU | TRANS (exp/rcp are TRANS-class)
#define M_DSR  0x100

// lgkm-only barrier (v7-proven): no vmcnt drain; memory ordering via clobber.
#define BAR() do { SB0(); \
                   asm volatile("s_waitcnt lgkmcnt(0)" ::: "memory"); \
                   __builtin_amdgcn_s_barrier(); SB0(); } while (0)

// sigmoid via exp2 + rcp (overflow-safe: rcp(inf)=0)
static __device__ __forceinline__ float sigm(float x) {
  float e = __builtin_amdgcn_exp2f(-1.442695040888963f * x);
  return __builtin_amdgcn_rcpf(1.0f + e);
}

__global__ void __launch_bounds__(512, 2) clstm_mfma8(
    const float* __restrict__ x,    // [B,S,F] f32
    const float* __restrict__ td,   // [B,S]   f32
    const float* __restrict__ Wi, const float* __restrict__ bi,
    const float* __restrict__ Wf, const float* __restrict__ bff,
    const float* __restrict__ Wo, const float* __restrict__ bo,
    const float* __restrict__ Wg, const float* __restrict__ bg,
    float* __restrict__ out)        // [B,S,H] f32
{
  const int b    = blockIdx.x;
  const int t    = threadIdx.x;
  const int wv   = t >> 6;
  const int l    = t & 63;
  const int col  = l & 15;
  const int quad = l >> 4;
  const int n    = wv * 16 + col;

  const float* Wptr[4] = {Wi, Wf, Wo, Wg};

  // Resident B-frags pinned to arch VGPRs (v4-proven).
  v8h Bh[4][4];
  v8h Bx[4][2];
#pragma unroll
  for (int g = 0; g < 4; ++g) {
    const float* W = Wptr[g];
#pragma unroll
    for (int kt = 0; kt < 4; ++kt) {
      v8h f;
#pragma unroll
      for (int j = 0; j < 8; ++j)
        f[j] = (_Float16)W[(64 + kt * 32 + quad * 8 + j) * H_N + n];
      Bh[g][kt] = f;
      PIN_V(Bh[g][kt]);
    }
#pragma unroll
    for (int kt = 0; kt < 2; ++kt) {
      v8h f;
#pragma unroll
      for (int j = 0; j < 8; ++j)
        f[j] = (_Float16)W[(kt * 32 + quad * 8 + j) * H_N + n];
      Bx[g][kt] = f;
      PIN_V(Bx[g][kt]);
    }
  }
  float bias[4];
#pragma unroll
  for (int g = 0; g < 4; ++g)
    bias[g] = (g == 0 ? bi : g == 1 ? bff : g == 2 ? bo : bg)[n];

  __shared__ alignas(16) _Float16 lds_h[2][H_N];  // double-buffered h (f16)
  __shared__ alignas(16) _Float16 lds_x[F_N];     // current x_t (f16)
  __shared__ alignas(16) _Float16 lds_dump[64];   // write sink for quads 1-3
  __shared__ float lds_td[S_N];

  lds_td[t] = td[b * S_N + t];
  if (t < 32) {
    const float* xr = x + (size_t)b * S_N * F_N;
    lds_x[2 * t]     = (_Float16)xr[2 * t];
    lds_x[2 * t + 1] = (_Float16)xr[2 * t + 1];
  }
  if (t < H_N) lds_h[0][t] = (_Float16)0.0f;
  // first BAR() covers setup visibility (lgkmcnt(0) + s_barrier)

  float h0v = 0.f, c0v = 0.f;
  float h_ev = 0.f, c_ev = 0.f;
  float sum_h = 0.f, sum_c = 0.f;
  float dt = 0.f, hdt = 0.f, d6 = 0.f, d6p = 0.f;
  const v4f zf = {0.f, 0.f, 0.f, 0.f};
  const v8h zh = {(_Float16)0, (_Float16)0, (_Float16)0, (_Float16)0,
                  (_Float16)0, (_Float16)0, (_Float16)0, (_Float16)0};
  // carried i/f/g accumulators (issued at stage top, consumed by S1 same
  // stage) + prev-stage A-frags + per-gate x-projections
  v4f ci2 = zf, ci3 = zf, cf2 = zf, cf3 = zf, cg2 = zf, cg3 = zf;
  v4f xpI = zf, xpF = zf, xpO = zf, xpG = zf;
  v8h ap0 = zh, ap1 = zh, ap2 = zh, ap3 = zh;
  float xn0 = 0.f, xn1 = 0.f;

  for (int s = 0; s < S_N; ++s) {
#pragma unroll
    for (int ode = 0; ode < 4; ++ode) {
#pragma unroll
      for (int st = 0; st < 4; ++st) {
        BAR();                                 // h(stage) now visible
        // ---- ds_reads: current A-frags ----
        const _Float16* hb = lds_h[st & 1];
        v8h ah0 = *(const v8h*)(hb + quad * 8);
        v8h ah1 = *(const v8h*)(hb + 32 + quad * 8);
        v8h ah2 = *(const v8h*)(hb + 64 + quad * 8);
        v8h ah3 = *(const v8h*)(hb + 96 + quad * 8);

        // ---- SGB pattern for this region: ds_reads first, 6-MFMA warm-up,
        //      then 1 MFMA : 4 VALU interleave (S1/tail fill the issue gaps)
        SGB(M_DSR, 4);
        SGB(M_MFMA, 6);
#pragma unroll
        for (int q = 0; q < 10; ++q) { SGB(M_MFMA, 1); SGB(M_VALU, 4); }

        // ---- ifg(prev stage) issue: reg-only (ap + xpI/F/G) ----
        if (st != 0 || ode != 0 || s != 0) {   // constant-folds except (0,0)
          ci2 = MFMA16(ap0, Bh[0][0], xpI);
          ci2 = MFMA16(ap1, Bh[0][1], ci2);
          ci3 = MFMA16(ap2, Bh[0][2], zf);
          ci3 = MFMA16(ap3, Bh[0][3], ci3);
          cf2 = MFMA16(ap0, Bh[1][0], xpF);
          cf2 = MFMA16(ap1, Bh[1][1], cf2);
          cf3 = MFMA16(ap2, Bh[1][2], zf);
          cf3 = MFMA16(ap3, Bh[1][3], cf3);
          cg2 = MFMA16(ap0, Bh[3][0], xpG);
          cg2 = MFMA16(ap1, Bh[3][1], cg2);
          cg3 = MFMA16(ap2, Bh[3][2], zf);
          cg3 = MFMA16(ap3, Bh[3][3], cg3);
        }

        if (ode == 0 && st == 0) {
          // per-timestep: dt scales, x-projection (8 MFMAs, after ifg so
          // ifg still sees the OLD xpI/F/G), next-x prefetch issue
          dt  = fminf(lds_td[s], 1.0f) * 0.25f;  // MAX_DT / ODE_STEPS
          hdt = 0.5f * dt;
          d6  = dt * (1.0f / 6.0f);
          v8h ax0 = *(const v8h*)(lds_x + quad * 8);
          v8h ax1 = *(const v8h*)(lds_x + 32 + quad * 8);
          {
            v4f cb = {bias[0], bias[0], bias[0], bias[0]};
            v4f a = MFMA16(ax0, Bx[0][0], cb);  xpI = MFMA16(ax1, Bx[0][1], a);
          }
          {
            v4f cb = {bias[1], bias[1], bias[1], bias[1]};
            v4f a = MFMA16(ax0, Bx[1][0], cb);  xpF = MFMA16(ax1, Bx[1][1], a);
          }
          {
            v4f cb = {bias[2], bias[2], bias[2], bias[2]};
            v4f a = MFMA16(ax0, Bx[2][0], cb);  xpO = MFMA16(ax1, Bx[2][1], a);
          }
          {
            v4f cb = {bias[3], bias[3], bias[3], bias[3]};
            v4f a = MFMA16(ax0, Bx[3][0], cb);  xpG = MFMA16(ax1, Bx[3][1], a);
          }
          xn0 = 0.f; xn1 = 0.f;
          if (t < 32 && s + 1 < S_N) {
            const float* xr = x + (size_t)(b * S_N + s + 1) * F_N;
            xn0 = xr[2 * t]; xn1 = xr[2 * t + 1];
          }
        }

        // ---- o(cur) issue: 4 independent 1-deep MFMAs ----
        v4f co0 = MFMA16(ah0, Bh[2][0], xpO);
        v4f co1 = MFMA16(ah1, Bh[2][1], zf);
        v4f co2 = MFMA16(ah2, Bh[2][2], zf);
        v4f co3 = MFMA16(ah3, Bh[2][3], zf);

        // ---- S1: deferred c-path of PREVIOUS stage (consumes this-top ifg
        //      results; SGB spreads these ops into the MFMA issue gaps) ----
        float tc;
        {
          const int pr = (st == 0) ? 3 : st - 1;   // prev stage's RK role
          float pi = ci2[0] + ci3[0];
          float pf = cf2[0] + cf3[0];
          float pg = cg2[0] + cg3[0];
          float ai = sigm(pi);
          float af = sigm(pf);
          float ag = fmaf(2.0f, sigm(2.0f * pg), -1.0f);   // tanh
          float kc = fmaf(ai, ag, (af - 1.0f) * c_ev);     // i*g + f*c - c
          float cnx;
          if (pr == 0)      { sum_c = kc;                      cnx = fmaf(hdt, kc, c0v); }
          else if (pr == 1) { sum_c = fmaf(2.f, kc, sum_c);    cnx = fmaf(hdt, kc, c0v); }
          else if (pr == 2) { sum_c = fmaf(2.f, kc, sum_c);    cnx = fmaf(dt, kc, c0v); }
          else {
            float sc = sum_c + kc;
            float dd = (ode == 0 && st == 0) ? d6p : d6;     // timestep crossing
            c0v = fmaf(dd, sc, c0v);
            cnx = c0v;
          }
          c_ev = cnx;
          tc = fmaf(2.0f, sigm(2.0f * c_ev), -1.0f);         // tanh(c_ev)
        }

        // ---- tail: o preact -> h update -> LDS write (no branch) ----
        float po = (co0[0] + co1[0]) + (co2[0] + co3[0]);
        float ao = sigm(po);
        float kh = fmaf(ao, tc, -h_ev);                      // o*tanh(c) - h
        float hnx;
        if (st == 0)      { sum_h = kh;                      hnx = fmaf(hdt, kh, h0v); }
        else if (st == 1) { sum_h = fmaf(2.f, kh, sum_h);    hnx = fmaf(hdt, kh, h0v); }
        else if (st == 2) { sum_h = fmaf(2.f, kh, sum_h);    hnx = fmaf(dt, kh, h0v); }
        else {
          float sh = sum_h + kh;
          h0v = fmaf(d6, sh, h0v);
          hnx = h0v;
        }
        h_ev = hnx;
        // predicated pointer select keeps this BB branch-free (SGB region)
        {
          _Float16* wp = (quad == 0) ? &lds_h[(st & 1) ^ 1][n] : &lds_dump[l];
          *wp = (_Float16)hnx;
        }

        if (ode == 3 && st == 3) {
          if (t < 32 && s + 1 < S_N) {
            lds_x[2 * t]     = (_Float16)xn0;   // reg-dep vmcnt wait here
            lds_x[2 * t + 1] = (_Float16)xn1;
          }
          if (quad == 0) out[(size_t)(b * S_N + s) * H_N + n] = h0v;
          d6p = d6;
        }

        // save A-frags for next stage's ifg issue (pure renames: ah* die)
        ap0 = ah0; ap1 = ah1; ap2 = ah2; ap3 = ah3;
      }
    }
  }
}

extern "C" void kernel_launch(void* const* d_in, const int* in_sizes, int n_in,
                              void* d_out, int out_size, void* d_ws, size_t ws_size,
                              hipStream_t stream) {
  (void)in_sizes; (void)n_in; (void)d_ws; (void)ws_size; (void)out_size;
  clstm_mfma8<<<B_N, 512, 0, stream>>>(
      (const float*)d_in[0],  // x
      (const float*)d_in[1],  // time_diffs
      (const float*)d_in[2], (const float*)d_in[3],   // W_i, b_i
      (const float*)d_in[4], (const float*)d_in[5],   // W_f, b_f
      (const float*)d_in[6], (const float*)d_in[7],   // W_o, b_o
      (const float*)d_in[8], (const float*)d_in[9],   // W_g, b_g
      (float*)d_out);
}

// Round 5
// 3371.554 us; speedup vs baseline: 1.0769x; 1.0769x over previous
//
#include <hip/hip_runtime.h>

// ContinuousLSTMLayer B=256,S=512,F=64,H=128; 8192 sequential RK4 stages.
// v9 = v7 + fully-independent MFMA streams (dependent-accept-stall theory).
// v7 PMC: stage 1107cy, pipe-busy 620cy (=model), ~490cy idle. All issue-order
// timelines predict ~850cy -> persistent ~250cy gap => suspect per-MFMA accept
// stalls from the 2-deep C-chains issued back-to-back (dependent MFMA
// issue-to-issue ~35-40cy > 19.4cy pipe rate; only 2 waves to interleave).
// Fix: 12 INDEPENDENT ifg accumulators (no C-chains at all), gate-interleaved
// issue order (i,f,g / i,f,g / ...) so consecutive MFMAs share no operands.
// S1 sums 4 partials per gate. o already 4-independent (v7). Everything else
// identical to v7 (ifg-at-top via ap regs, lgkm-only barrier, 1-stage-deferred
// c-path, amortized x-projection, h f16 double-buffer in LDS).
// v8 lesson: no SGB grafts, no predicated dump-writes (caused 4.2M bank
// conflicts + regression).

#define B_N 256
#define S_N 512
#define F_N 64
#define H_N 128

typedef _Float16 v8h __attribute__((ext_vector_type(8)));
typedef float v4f __attribute__((ext_vector_type(4)));

#define PIN_V(x) asm("" : "+v"(x))
#define MFMA16(a, b, c) __builtin_amdgcn_mfma_f32_16x16x32_f16((a), (b), (c), 0, 0, 0)
#define SB0() __builtin_amdgcn_sched_barrier(0)
// lgkm-only barrier (v7-proven): no vmcnt drain; memory ordering via clobber.
#define BAR() do { SB0(); \
                   asm volatile("s_waitcnt lgkmcnt(0)" ::: "memory"); \
                   __builtin_amdgcn_s_barrier(); SB0(); } while (0)

// sigmoid via exp2 + rcp (overflow-safe: rcp(inf)=0)
static __device__ __forceinline__ float sigm(float x) {
  float e = __builtin_amdgcn_exp2f(-1.442695040888963f * x);
  return __builtin_amdgcn_rcpf(1.0f + e);
}

__global__ void __launch_bounds__(512, 2) clstm_mfma9(
    const float* __restrict__ x,    // [B,S,F] f32
    const float* __restrict__ td,   // [B,S]   f32
    const float* __restrict__ Wi, const float* __restrict__ bi,
    const float* __restrict__ Wf, const float* __restrict__ bff,
    const float* __restrict__ Wo, const float* __restrict__ bo,
    const float* __restrict__ Wg, const float* __restrict__ bg,
    float* __restrict__ out)        // [B,S,H] f32
{
  const int b    = blockIdx.x;
  const int t    = threadIdx.x;
  const int wv   = t >> 6;
  const int l    = t & 63;
  const int col  = l & 15;
  const int quad = l >> 4;
  const int n    = wv * 16 + col;

  const float* Wptr[4] = {Wi, Wf, Wo, Wg};

  // Resident B-frags pinned to arch VGPRs (v4-proven).
  v8h Bh[4][4];
  v8h Bx[4][2];
#pragma unroll
  for (int g = 0; g < 4; ++g) {
    const float* W = Wptr[g];
#pragma unroll
    for (int kt = 0; kt < 4; ++kt) {
      v8h f;
#pragma unroll
      for (int j = 0; j < 8; ++j)
        f[j] = (_Float16)W[(64 + kt * 32 + quad * 8 + j) * H_N + n];
      Bh[g][kt] = f;
      PIN_V(Bh[g][kt]);
    }
#pragma unroll
    for (int kt = 0; kt < 2; ++kt) {
      v8h f;
#pragma unroll
      for (int j = 0; j < 8; ++j)
        f[j] = (_Float16)W[(kt * 32 + quad * 8 + j) * H_N + n];
      Bx[g][kt] = f;
      PIN_V(Bx[g][kt]);
    }
  }
  float bias[4];
#pragma unroll
  for (int g = 0; g < 4; ++g)
    bias[g] = (g == 0 ? bi : g == 1 ? bff : g == 2 ? bo : bg)[n];

  __shared__ alignas(16) _Float16 lds_h[2][H_N];  // double-buffered h (f16)
  __shared__ alignas(16) _Float16 lds_x[F_N];     // current x_t (f16)
  __shared__ float lds_td[S_N];

  lds_td[t] = td[b * S_N + t];
  if (t < 32) {
    const float* xr = x + (size_t)b * S_N * F_N;
    lds_x[2 * t]     = (_Float16)xr[2 * t];
    lds_x[2 * t + 1] = (_Float16)xr[2 * t + 1];
  }
  if (t < H_N) lds_h[0][t] = (_Float16)0.0f;
  // first BAR() covers setup visibility (lgkmcnt(0) + s_barrier)

  float h0v = 0.f, c0v = 0.f;
  float h_ev = 0.f, c_ev = 0.f;
  float sum_h = 0.f, sum_c = 0.f;
  float dt = 0.f, hdt = 0.f, d6 = 0.f, d6p = 0.f;
  const v4f zf = {0.f, 0.f, 0.f, 0.f};
  const v8h zh = {(_Float16)0, (_Float16)0, (_Float16)0, (_Float16)0,
                  (_Float16)0, (_Float16)0, (_Float16)0, (_Float16)0};
  // 12 fully-independent ifg carries (issued at stage top, consumed by S1
  // same stage) + prev-stage A-frags + per-gate x-projections
  v4f iA = zf, iB = zf, iC = zf, iD = zf;
  v4f fA = zf, fB = zf, fC = zf, fD = zf;
  v4f gA = zf, gB = zf, gC = zf, gD = zf;
  v4f xpI = zf, xpF = zf, xpO = zf, xpG = zf;
  v8h ap0 = zh, ap1 = zh, ap2 = zh, ap3 = zh;
  float xn0 = 0.f, xn1 = 0.f;

  for (int s = 0; s < S_N; ++s) {
#pragma unroll
    for (int ode = 0; ode < 4; ++ode) {
#pragma unroll
      for (int st = 0; st < 4; ++st) {
        BAR();                                 // h(stage) now visible
        // ---- ds_reads: current A-frags ----
        const _Float16* hb = lds_h[st & 1];
        v8h ah0 = *(const v8h*)(hb + quad * 8);
        v8h ah1 = *(const v8h*)(hb + 32 + quad * 8);
        v8h ah2 = *(const v8h*)(hb + 64 + quad * 8);
        v8h ah3 = *(const v8h*)(hb + 96 + quad * 8);

        // ---- ifg(prev stage) issue: 12 INDEPENDENT MFMAs, gate-interleaved
        //      so no consecutive pair shares accumulator or A operand ----
        if (st != 0 || ode != 0 || s != 0) {   // constant-folds except (0,0)
          iA = MFMA16(ap0, Bh[0][0], xpI);
          fA = MFMA16(ap0, Bh[1][0], xpF);
          gA = MFMA16(ap0, Bh[3][0], xpG);
          iB = MFMA16(ap1, Bh[0][1], zf);
          fB = MFMA16(ap1, Bh[1][1], zf);
          gB = MFMA16(ap1, Bh[3][1], zf);
          iC = MFMA16(ap2, Bh[0][2], zf);
          fC = MFMA16(ap2, Bh[1][2], zf);
          gC = MFMA16(ap2, Bh[3][2], zf);
          iD = MFMA16(ap3, Bh[0][3], zf);
          fD = MFMA16(ap3, Bh[1][3], zf);
          gD = MFMA16(ap3, Bh[3][3], zf);
        }
        SB0();                                 // pin ifg before xp/o

        if (ode == 0 && st == 0) {
          // per-timestep: dt scales, x-projection (8 MFMAs, after ifg so
          // ifg still sees the OLD xpI/F/G), next-x prefetch issue
          dt  = fminf(lds_td[s], 1.0f) * 0.25f;  // MAX_DT / ODE_STEPS
          hdt = 0.5f * dt;
          d6  = dt * (1.0f / 6.0f);
          v8h ax0 = *(const v8h*)(lds_x + quad * 8);
          v8h ax1 = *(const v8h*)(lds_x + 32 + quad * 8);
          {
            v4f cb = {bias[0], bias[0], bias[0], bias[0]};
            v4f a = MFMA16(ax0, Bx[0][0], cb);  xpI = MFMA16(ax1, Bx[0][1], a);
          }
          {
            v4f cb = {bias[1], bias[1], bias[1], bias[1]};
            v4f a = MFMA16(ax0, Bx[1][0], cb);  xpF = MFMA16(ax1, Bx[1][1], a);
          }
          {
            v4f cb = {bias[2], bias[2], bias[2], bias[2]};
            v4f a = MFMA16(ax0, Bx[2][0], cb);  xpO = MFMA16(ax1, Bx[2][1], a);
          }
          {
            v4f cb = {bias[3], bias[3], bias[3], bias[3]};
            v4f a = MFMA16(ax0, Bx[3][0], cb);  xpG = MFMA16(ax1, Bx[3][1], a);
          }
          xn0 = 0.f; xn1 = 0.f;
          if (t < 32 && s + 1 < S_N) {
            const float* xr = x + (size_t)(b * S_N + s + 1) * F_N;
            xn0 = xr[2 * t]; xn1 = xr[2 * t + 1];
          }
        }

        // ---- o(cur) issue: 4 independent 1-deep MFMAs ----
        v4f co0 = MFMA16(ah0, Bh[2][0], xpO);
        v4f co1 = MFMA16(ah1, Bh[2][1], zf);
        v4f co2 = MFMA16(ah2, Bh[2][2], zf);
        v4f co3 = MFMA16(ah3, Bh[2][3], zf);
        SB0();                                 // o issued before S1's stall

        // ---- S1: deferred c-path of PREVIOUS stage (consumes this-top ifg
        //      results; 4-term sums per gate) ----
        float tc;
        {
          const int pr = (st == 0) ? 3 : st - 1;   // prev stage's RK role
          float pi = (iA[0] + iB[0]) + (iC[0] + iD[0]);
          float pf = (fA[0] + fB[0]) + (fC[0] + fD[0]);
          float pg = (gA[0] + gB[0]) + (gC[0] + gD[0]);
          float ai = sigm(pi);
          float af = sigm(pf);
          float ag = fmaf(2.0f, sigm(2.0f * pg), -1.0f);   // tanh
          float kc = fmaf(ai, ag, (af - 1.0f) * c_ev);     // i*g + f*c - c
          float cnx;
          if (pr == 0)      { sum_c = kc;                      cnx = fmaf(hdt, kc, c0v); }
          else if (pr == 1) { sum_c = fmaf(2.f, kc, sum_c);    cnx = fmaf(hdt, kc, c0v); }
          else if (pr == 2) { sum_c = fmaf(2.f, kc, sum_c);    cnx = fmaf(dt, kc, c0v); }
          else {
            float sc = sum_c + kc;
            float dd = (ode == 0 && st == 0) ? d6p : d6;     // timestep crossing
            c0v = fmaf(dd, sc, c0v);
            cnx = c0v;
          }
          c_ev = cnx;
          tc = fmaf(2.0f, sigm(2.0f * c_ev), -1.0f);         // tanh(c_ev)
        }

        // ---- tail: o preact -> h update -> LDS write ----
        float po = (co0[0] + co1[0]) + (co2[0] + co3[0]);
        float ao = sigm(po);
        float kh = fmaf(ao, tc, -h_ev);                      // o*tanh(c) - h
        float hnx;
        if (st == 0)      { sum_h = kh;                      hnx = fmaf(hdt, kh, h0v); }
        else if (st == 1) { sum_h = fmaf(2.f, kh, sum_h);    hnx = fmaf(hdt, kh, h0v); }
        else if (st == 2) { sum_h = fmaf(2.f, kh, sum_h);    hnx = fmaf(dt, kh, h0v); }
        else {
          float sh = sum_h + kh;
          h0v = fmaf(d6, sh, h0v);
          hnx = h0v;
        }
        h_ev = hnx;
        if (quad == 0) lds_h[(st & 1) ^ 1][n] = (_Float16)hnx;

        if (ode == 3 && st == 3) {
          if (t < 32 && s + 1 < S_N) {
            lds_x[2 * t]     = (_Float16)xn0;   // reg-dep vmcnt wait here
            lds_x[2 * t + 1] = (_Float16)xn1;
          }
          if (quad == 0) out[(size_t)(b * S_N + s) * H_N + n] = h0v;
          d6p = d6;
        }

        // save A-frags for next stage's ifg issue (pure renames: ah* die)
        ap0 = ah0; ap1 = ah1; ap2 = ah2; ap3 = ah3;
      }
    }
  }
}

extern "C" void kernel_launch(void* const* d_in, const int* in_sizes, int n_in,
                              void* d_out, int out_size, void* d_ws, size_t ws_size,
                              hipStream_t stream) {
  (void)in_sizes; (void)n_in; (void)d_ws; (void)ws_size; (void)out_size;
  clstm_mfma9<<<B_N, 512, 0, stream>>>(
      (const float*)d_in[0],  // x
      (const float*)d_in[1],  // time_diffs
      (const float*)d_in[2], (const float*)d_in[3],   // W_i, b_i
      (const float*)d_in[4], (const float*)d_in[5],   // W_f, b_f
      (const float*)d_in[6], (const float*)d_in[7],   // W_o, b_o
      (const float*)d_in[8], (const float*)d_in[9],   // W_g, b_g
      (float*)d_out);
}